// Round 1
// baseline (122.835 us; speedup 1.0000x reference)
//
#include <hip/hip_runtime.h>
#include <cstdint>

// One thread per point. Memory-bound: 40 B read + 28 B write per point.
__global__ __launch_bounds__(256) void gs_project_kernel(
    const float* __restrict__ points,   // N*3
    const float* __restrict__ quats,    // N*4
    const float* __restrict__ scales,   // N*3
    const float* __restrict__ E,        // 16 (4x4 row-major extrinsic)
    const float* __restrict__ K,        // 12 (3x4 row-major intrinsic)
    float* __restrict__ out,            // [uv: 2N][z: N][cov: 4N]
    int n)
{
    int i = blockIdx.x * blockDim.x + threadIdx.x;
    if (i >= n) return;

    // Broadcast loads of the small matrices (same address across the wave -> cached).
    const float e00=E[0],  e01=E[1],  e02=E[2],  e03=E[3];
    const float e10=E[4],  e11=E[5],  e12=E[6],  e13=E[7];
    const float e20=E[8],  e21=E[9],  e22=E[10], e23=E[11];
    const float e30=E[12], e31=E[13], e32=E[14], e33=E[15];
    const float k00=K[0],  k01=K[1],  k02=K[2],  k03=K[3];
    const float k10=K[4],  k11=K[5],  k12=K[6],  k13=K[7];
    const float k20=K[8],  k21=K[9],  k22=K[10], k23=K[11];

    const float px = points[3*i+0], py = points[3*i+1], pz = points[3*i+2];
    const float4 q4 = ((const float4*)quats)[i];
    const float sx = scales[3*i+0], sy = scales[3*i+1], sz = scales[3*i+2];

    // --- quaternion normalize + rotation matrix ---
    const float qn = sqrtf(q4.x*q4.x + q4.y*q4.y + q4.z*q4.z + q4.w*q4.w);
    const float w = q4.x/qn, x = q4.y/qn, y = q4.z/qn, z = q4.w/qn;

    const float r00 = 1.f - 2.f*(y*y + z*z);
    const float r01 = 2.f*(x*y - w*z);
    const float r02 = 2.f*(x*z + w*y);
    const float r10 = 2.f*(x*y + w*z);
    const float r11 = 1.f - 2.f*(x*x + z*z);
    const float r12 = 2.f*(y*z - w*x);
    const float r20 = 2.f*(x*z - w*y);
    const float r21 = 2.f*(y*z + w*x);
    const float r22 = 1.f - 2.f*(x*x + y*y);

    // M = R * scales (column-wise broadcast)
    const float m00=r00*sx, m01=r01*sy, m02=r02*sz;
    const float m10=r10*sx, m11=r11*sy, m12=r12*sz;
    const float m20=r20*sx, m21=r21*sy, m22=r22*sz;

    // cov3d = M @ M^T (symmetric)
    const float c00 = m00*m00 + m01*m01 + m02*m02;
    const float c01 = m00*m10 + m01*m11 + m02*m12;
    const float c02 = m00*m20 + m01*m21 + m02*m22;
    const float c11 = m10*m10 + m11*m11 + m12*m12;
    const float c12 = m10*m20 + m11*m21 + m12*m22;
    const float c22 = m20*m20 + m21*m21 + m22*m22;

    // --- camera transform (cam = E @ [p,1]) ---
    const float camx = e00*px + e01*py + e02*pz + e03;
    const float camy = e10*px + e11*py + e12*pz + e13;
    const float camz = e20*px + e21*py + e22*pz + e23;
    const float camw = e30*px + e31*py + e32*pz + e33;
    const float cx = camx/camw, cy = camy/camw, cz = camz/camw;

    // --- projection: proj = K @ [cam3,1] ---
    const float p0 = k00*cx + k01*cy + k02*cz + k03;
    const float p1 = k10*cx + k11*cy + k12*cz + k13;
    const float p2 = k20*cx + k21*cy + k22*cz + k23;
    const float u = p0/p2, v = p1/p2;

    // --- Jacobian (row 2 is zero) ---
    const float fx = k00, fy = k11;
    const float czz = cz*cz;
    const float j00 = fx/cz;
    const float j02 = (-fx*cx)/czz;
    const float j11 = fy/cz;
    const float j12 = (-fy*cy)/czz;

    // T = J @ E[:3,:3]  (since T[i,k] = sum_j J[i,j] * W[k,j], W = E3^T)
    const float t00 = j00*e00 + j02*e20;
    const float t01 = j00*e01 + j02*e21;
    const float t02 = j00*e02 + j02*e22;
    const float t10 = j11*e10 + j12*e20;
    const float t11 = j11*e11 + j12*e21;
    const float t12 = j11*e12 + j12*e22;

    // cov2d = T2 @ cov3d @ T2^T
    const float a00 = t00*c00 + t01*c01 + t02*c02;
    const float a01 = t00*c01 + t01*c11 + t02*c12;
    const float a02 = t00*c02 + t01*c12 + t02*c22;
    const float a10 = t10*c00 + t11*c01 + t12*c02;
    const float a11 = t10*c01 + t11*c11 + t12*c12;
    const float a12 = t10*c02 + t11*c12 + t12*c22;
    const float v00 = a00*t00 + a01*t01 + a02*t02;
    const float v01 = a00*t10 + a01*t11 + a02*t12;
    const float v10 = a10*t00 + a11*t01 + a12*t02;
    const float v11 = a10*t10 + a11*t11 + a12*t12;

    // --- stores ---
    ((float2*)out)[i] = make_float2(u, v);          // projected_points, offset 0
    out[2*(size_t)n + i] = camz;                    // z_component = cam[:,2] (pre-divide)
    float* cov_out = out + 3*(size_t)n;             // 16B-aligned for n % 4 == 0
    ((float4*)cov_out)[i] = make_float4(v00, v01, v10, v11);
}

extern "C" void kernel_launch(void* const* d_in, const int* in_sizes, int n_in,
                              void* d_out, int out_size, void* d_ws, size_t ws_size,
                              hipStream_t stream) {
    const float* points = (const float*)d_in[0];
    const float* quats  = (const float*)d_in[1];
    const float* scales = (const float*)d_in[2];
    const float* E      = (const float*)d_in[3];
    const float* K      = (const float*)d_in[4];
    float* out = (float*)d_out;

    const int n = in_sizes[0] / 3;
    const int block = 256;
    const int grid = (n + block - 1) / block;
    gs_project_kernel<<<grid, block, 0, stream>>>(points, quats, scales, E, K, out, n);
}